// Round 1
// baseline (204.356 us; speedup 1.0000x reference)
//
#include <hip/hip_runtime.h>
#include <math.h>

#define CC 512
#define HH 64
#define WW 96
#define NN 16
#define HW (HH*WW)        // 6144
#define NA 9
#define NLOC 36
#define NSC 18
#define NOUT 54           // 36 loc + 18 score

// ---------------------------------------------------------------------------
// Kernel 1: transpose weights into wT[c][o] (o: 0..35 = loc, 36..53 = score)
// so the main loop reads 54 contiguous wave-uniform floats per channel.
// ---------------------------------------------------------------------------
__global__ void transpose_w_kernel(const float* __restrict__ lw,
                                   const float* __restrict__ sw,
                                   float* __restrict__ wT) {
    int i = blockIdx.x * 256 + threadIdx.x;   // over CC*NOUT
    if (i >= CC * NOUT) return;
    int c = i / NOUT, o = i % NOUT;
    float v = (o < NLOC) ? lw[o * CC + c] : sw[(o - NLOC) * CC + c];
    wT[c * NOUT + o] = v;
}

// ---------------------------------------------------------------------------
// Kernel 2: anchors (55296, 4). Pure closed form, matches numpy f64->f32.
// ---------------------------------------------------------------------------
__global__ void anchors_kernel(float* __restrict__ out3) {
    int t = blockIdx.x * 256 + threadIdx.x;   // over HW*NA
    if (t >= HW * NA) return;
    int a   = t % NA;
    int rem = t / NA;
    int h = rem / WW, w = rem % WW;
    int ri = a / 3, si = a % 3;
    const double ratios[3] = {0.5, 1.0, 2.0};
    const double scales[3] = {8.0, 16.0, 32.0};
    double ha = 16.0 * scales[si] * sqrt(ratios[ri]);
    double wa = 16.0 * scales[si] * sqrt(1.0 / ratios[ri]);
    float y1 = (float)(8.0 - ha * 0.5);
    float x1 = (float)(8.0 - wa * 0.5);
    float y2 = (float)(8.0 + ha * 0.5);
    float x2 = (float)(8.0 + wa * 0.5);
    float sy = (float)(h * 16);
    float sx = (float)(w * 16);
    float4 v = make_float4(sy + y1, sx + x1, sy + y2, sx + x2);
    *reinterpret_cast<float4*>(out3 + (size_t)t * 4) = v;
}

// ---------------------------------------------------------------------------
// Kernel 3: main. One thread per (n,h,w) position. 54 fp32 accumulators.
// x reads coalesced (lane = consecutive w). Weights read wave-uniform from
// wT (contiguous 54 floats per c) -> scalar loads, broadcast via SGPR.
// ---------------------------------------------------------------------------
__launch_bounds__(256)
__global__ void rpn_main_kernel(const float* __restrict__ x,
                                const float* __restrict__ wT,
                                const float* __restrict__ lb,
                                const float* __restrict__ sb,
                                float* __restrict__ out0,   // rpn_loc
                                float* __restrict__ out1,   // rpn_score
                                float* __restrict__ out2) { // rpn_fg_scores
    int p = blockIdx.x * 256 + threadIdx.x;   // over NN*HW
    if (p >= NN * HW) return;
    int n   = p / HW;
    int rem = p % HW;
    const float* xp = x + (size_t)n * CC * HW + rem;

    float acc[NOUT];
    #pragma unroll
    for (int o = 0; o < NOUT; ++o) acc[o] = 0.0f;

    #pragma unroll 4
    for (int c = 0; c < CC; ++c) {
        float xv = xp[(size_t)c * HW];
        const float* wrow = wT + c * NOUT;   // wave-uniform, contiguous
        #pragma unroll
        for (int o = 0; o < NOUT; ++o)
            acc[o] = fmaf(xv, wrow[o], acc[o]);
    }

    // epilogue: biases + stores
    size_t base0 = (size_t)p * NLOC;
    #pragma unroll
    for (int o = 0; o < NLOC; ++o)
        out0[base0 + o] = acc[o] + lb[o];

    float sc[NSC];
    size_t base1 = (size_t)p * NSC;
    #pragma unroll
    for (int o = 0; o < NSC; ++o) {
        sc[o] = acc[NLOC + o] + sb[o];
        out1[base1 + o] = sc[o];
    }

    size_t base2 = (size_t)p * NA;
    #pragma unroll
    for (int a = 0; a < NA; ++a) {
        float d = sc[2 * a] - sc[2 * a + 1];      // s0 - s1
        out2[base2 + a] = 1.0f / (1.0f + __expf(d));  // softmax[...,1]
    }
}

extern "C" void kernel_launch(void* const* d_in, const int* in_sizes, int n_in,
                              void* d_out, int out_size, void* d_ws, size_t ws_size,
                              hipStream_t stream) {
    const float* x  = (const float*)d_in[0];
    const float* lw = (const float*)d_in[1];
    const float* lb = (const float*)d_in[2];
    const float* sw = (const float*)d_in[3];
    const float* sb = (const float*)d_in[4];

    float* out0 = (float*)d_out;                          // (16, 55296, 4)  = 3538944
    float* out1 = out0 + (size_t)NN * HW * NLOC;          // (16, 64, 96,18) = 1769472
    float* out2 = out1 + (size_t)NN * HW * NSC;           // (16, 55296)     =  884736
    float* out3 = out2 + (size_t)NN * HW * NA;            // (55296, 4)      =  221184

    float* wT = (float*)d_ws;                             // CC*NOUT floats = 110592 B

    int grid_t = (CC * NOUT + 255) / 256;                 // 108
    transpose_w_kernel<<<grid_t, 256, 0, stream>>>(lw, sw, wT);

    int grid_a = (HW * NA + 255) / 256;                   // 216
    anchors_kernel<<<grid_a, 256, 0, stream>>>(out3);

    int grid_m = (NN * HW + 255) / 256;                   // 384
    rpn_main_kernel<<<grid_m, 256, 0, stream>>>(x, wT, lb, sb, out0, out1, out2);
}